// Round 1
// baseline (345.897 us; speedup 1.0000x reference)
//
#include <hip/hip_runtime.h>
#include <math.h>

#define T_LEN 512
#define B_N   1024
#define K_N   48
#define START_TAG (K_N - 2)
#define STOP_TAG  (K_N - 1)
#define NEG   -10000.0f

// 2-wave cooperative split-K CRF forward.
// One workgroup (128 thr = 2 waves) per batch. Lane j of BOTH waves holds a
// replicated q_j = exp(alpha_j - C). Wave h owns k-range [24h, 24h+24):
//   partial_j^h = sum_{k in range} E[j,k] * q_k     (24 readlane + 24 fma)
// Partials exchanged via double-buffered LDS, ONE __syncthreads per step.
// Both waves then rebuild q identically (bitwise: fp add is commutative,
// feat/scale inputs identical), so no re-broadcast is needed.
// Rationale: with 1024 waves = 1 wave/SIMD the old kernel could not hide
// dependent-latency stalls (VALUBusy 61.5%). 2048 waves = 2/SIMD lets waves
// of DIFFERENT workgroups fill each other's barrier/LDS/dep stalls, and
// per-wave issue per step is halved.
// Note k=47 (STOP column) is included in wave1's range: E[j,47]=exp(-1e4)=0
// in fp32, so it contributes exactly 0 and keeps both waves symmetric.
//
// Carried-over load-bearing details from the single-wave version:
//  * explicit waves_per_eu (now (2,2)): default budgeting spills E to scratch.
//  * loads UNCONDITIONAL with clamped indices, no branches around barriers.
//  * NO register rotation: fixed 512-step trip, statically-indexed f0/f1
//    ping-pong arrays, per-step `t<len` cndmask reproduces the mask(freeze)
//    semantics of the reference.

#define REP24(M) M(0)M(1)M(2)M(3)M(4)M(5)M(6)M(7)M(8)M(9)M(10)M(11) \
  M(12)M(13)M(14)M(15)M(16)M(17)M(18)M(19)M(20)M(21)M(22)M(23)

#define DECL_S(k) const float s##k = __uint_as_float(__builtin_amdgcn_readlane(__float_as_uint(q), k0 + k));

#define FMA4(i0,i1,i2,i3) \
        a0 = fmaf(E##i0, s##i0, a0); a1 = fmaf(E##i1, s##i1, a1); \
        a2 = fmaf(E##i2, s##i2, a2); a3 = fmaf(E##i3, s##i3, a3);

// One recursion step at time TT consuming raw feat value FVAL.
// Invariant alpha_j = C + log(q_j), updated only when TT < len (wave-uniform).
#define STEP(TT, FVAL) do { \
        REP24(DECL_S) \
        const float sn   = __uint_as_float(__builtin_amdgcn_readlane(__float_as_uint(q), 0)); \
        const bool  live = (sn > 0.0f);                     /* false only at t==0 */ \
        const float inv  = live ? __builtin_amdgcn_rcpf(sn) : 1.0f; \
        const float dC   = live ? __logf(sn) : 0.0f; \
        const bool  on   = ((TT) < len); \
        C += on ? dC : 0.0f; \
        const float scale = __expf(FVAL) * inv; \
        float a0 = 0.f, a1 = 0.f, a2 = 0.f, a3 = 0.f; \
        FMA4(0,1,2,3)     FMA4(4,5,6,7)     FMA4(8,9,10,11) \
        FMA4(12,13,14,15) FMA4(16,17,18,19) FMA4(20,21,22,23) \
        const float partial = (a0 + a1) + (a2 + a3); \
        part[(TT) & 1][wid][lane] = partial; \
        __syncthreads(); \
        const float w = partial + part[(TT) & 1][wid ^ 1][lane]; \
        q = on ? w * scale : q; \
    } while (0)

__global__ __launch_bounds__(128)
__attribute__((amdgpu_waves_per_eu(2, 2)))
void crf_fused_kernel(
    const float* __restrict__ feats,    // (T, B, K)
    const float* __restrict__ trans,    // (K, K)
    const int*   __restrict__ tags,     // (B, T)
    const int*   __restrict__ lengths,  // (B,)
    float* __restrict__ out)
{
    const int b      = blockIdx.x;
    const int tid    = threadIdx.x;
    const int lane   = tid & 63;
    const int wid    = tid >> 6;          // 0 or 1
    const int k0     = wid * 24;          // this wave's k-range base (uniform)
    const int len    = lengths[b];
    const int lm1    = len - 1;
    const int lane_c = (lane < K_N) ? lane : (K_N - 1);   // clamp: addrs valid

    __shared__ float part[2][2][64];      // [phase][wave][lane], 1 KiB

    // This wave's 24-column slice of E = exp(trans), row lane_c.
    // Lanes >= K_N compute junk but finite q forever — never readlane'd
    // (k0+k <= 47), never stored.
    const float* tr = trans + lane_c * K_N + k0;
#define DECL_E(k) const float E##k = __expf(tr[k]);
    REP24(DECL_E)
#undef DECL_E

    const float*  fb = feats + (size_t)b * K_N;
    const size_t  sT = (size_t)B_N * K_N;

    float q = (lane == START_TAG) ? 1.0f : 0.0f;
    float C = 0.0f;

    // Ping-pong prefetch buffers, all statically indexed (registers).
    // Both waves load the full feat row (twin loads are L1/L2 hits; we are
    // at 4% of HBM peak so the duplication is free).
    float f0[8], f1[8];
    #pragma unroll
    for (int i = 0; i < 8; ++i) {
        int r = (i < lm1) ? i : lm1;
        f0[i] = fb[(size_t)r * sT + lane_c];
    }

    #pragma unroll 1
    for (int blk = 0; blk < T_LEN / 16; ++blk) {
        const int t0 = blk * 16;
        // Phase A: prefetch rows t0+8..t0+15 into f1; run steps t0..t0+7 on f0.
        #pragma unroll
        for (int i = 0; i < 8; ++i) {
            int r = t0 + 8 + i; r = (r < lm1) ? r : lm1;
            f1[i] = fb[(size_t)r * sT + lane_c];
        }
        #pragma unroll
        for (int i = 0; i < 8; ++i) STEP(t0 + i, f0[i]);
        // Phase B: prefetch rows t0+16..t0+23 into f0; run steps t0+8..t0+15 on f1.
        #pragma unroll
        for (int i = 0; i < 8; ++i) {
            int r = t0 + 16 + i; r = (r < lm1) ? r : lm1;
            f0[i] = fb[(size_t)r * sT + lane_c];
        }
        #pragma unroll
        for (int i = 0; i < 8; ++i) STEP(t0 + 8 + i, f1[i]);
    }
    // Both waves executed exactly 512 barriers; wave 1 is done.

    if (wid == 0) {
        // log_z = C + log(q_j) + trans[STOP, j], logsumexp over lanes.
        float v = (lane < K_N && q > 0.0f)
                ? C + __logf(q) + trans[STOP_TAG * K_N + lane] : -INFINITY;
        float mz = v;
        #pragma unroll
        for (int off = 32; off >= 1; off >>= 1)
            mz = fmaxf(mz, __shfl_xor(mz, off));
        float e = __expf(v - mz);
        float se = e;
        #pragma unroll
        for (int off = 32; off >= 1; off >>= 1)
            se += __shfl_xor(se, off);
        float log_z = mz + __logf(se);

        // Gold path score: lanes stripe over t.
        float gsum = 0.0f;
        for (int t = lane; t < len; t += 64) {
            int next = tags[(size_t)b * T_LEN + t];
            int prev = (t == 0) ? START_TAG : tags[(size_t)b * T_LEN + t - 1];
            gsum += trans[next * K_N + prev]
                  + fb[(size_t)t * sT + next];
        }
        #pragma unroll
        for (int off = 32; off >= 1; off >>= 1)
            gsum += __shfl_xor(gsum, off);

        if (lane == 0) {
            int last = tags[(size_t)b * T_LEN + len - 1];
            float gold = gsum + trans[STOP_TAG * K_N + last];
            atomicAdd(out, log_z - gold);
        }
    }
}

extern "C" void kernel_launch(void* const* d_in, const int* in_sizes, int n_in,
                              void* d_out, int out_size, void* d_ws, size_t ws_size,
                              hipStream_t stream) {
    const float* feats   = (const float*)d_in[0];
    const float* trans   = (const float*)d_in[1];
    const int*   tags    = (const int*)d_in[2];
    const int*   lengths = (const int*)d_in[3];
    float* out = (float*)d_out;

    hipMemsetAsync(out, 0, sizeof(float) * out_size, stream);
    crf_fused_kernel<<<B_N, 128, 0, stream>>>(feats, trans, tags, lengths, out);
}

// Round 2
// 285.875 us; speedup vs baseline: 1.2100x; 1.2100x over previous
//
#include <hip/hip_runtime.h>
#include <math.h>

#define T_LEN 512
#define B_N   1024
#define K_N   48
#define START_TAG (K_N - 2)
#define STOP_TAG  (K_N - 1)
#define NEG   -10000.0f

// Single-wave CRF forward, LDS-broadcast variant.
// One wave (64 thr) per batch. EVERY lane holds the full replicated vector
// q (Q0..Q47, VGPRs), q_j = exp(alpha_j - C). Per step:
//   1. lane j: w_j = sum_{k<47} E[j,k] * Q_k      (47 VGPR-VGPR fma, no readlane)
//   2. norm in-lane: inv = rcp(Q0), dC = log(Q0)  (Q0 replicated -> uniform)
//   3. qn_j = on ? w_j * exp(f)*inv : qown        (freeze == reference mask)
//   4. ds_write_b32 lane slot; s_waitcnt lgkmcnt(0); 12x ds_read_b128
//      (same addr across lanes = broadcast, conflict-free) -> next Q replica.
// Rationale vs R0 (136.5us, 640cy/step, VALUBusy 61.5% = 394 busy cy): the 47
// v_readlane broadcasts cost ~5cy each (~250cy/step). The LDS broadcast costs
// ~12 reads + write + drain (~190cy incl latency) and moves norm in-lane.
// Rationale vs R1 (237us): NO barrier — single wave, lgkmcnt-only ordering;
// DS ops are in-order per wave, explicit lgkmcnt(0) after the write.
//
// Load-bearing details:
//  * asm lgkmcnt(0), NOT __syncthreads(): syncthreads drains vmcnt(0) too and
//    would expose full HBM latency of the feat prefetch every step (R6: 355us).
//  * waves_per_eu(1,1): default VGPR budget spills E/Q to scratch.
//  * feat loads UNCONDITIONAL (clamped indices), issued 8 steps ahead,
//    statically-indexed f0/f1 ping-pong (no register rotation, R6).
//  * all LDS addresses compile-time constant (step parity from unrolled index).
//  * lanes >= K_N mirror lane 47 exactly (replicated inputs) — finite, never read.

#define REP47(M) M(0)M(1)M(2)M(3)M(4)M(5)M(6)M(7)M(8)M(9)M(10)M(11)M(12) \
  M(13)M(14)M(15)M(16)M(17)M(18)M(19)M(20)M(21)M(22)M(23)M(24)M(25)M(26) \
  M(27)M(28)M(29)M(30)M(31)M(32)M(33)M(34)M(35)M(36)M(37)M(38)M(39)M(40) \
  M(41)M(42)M(43)M(44)M(45)M(46)

#define FMA4(k0,k1,k2,k3) \
        a0 = fmaf(E##k0, Q##k0, a0); a1 = fmaf(E##k1, Q##k1, a1); \
        a2 = fmaf(E##k2, Q##k2, a2); a3 = fmaf(E##k3, Q##k3, a3);

// Reload the replicated Q vector from LDS buffer P (4 values per b128 read).
#define LQ(P, p, A0,A1,A2,A3) { \
        const float4 v = *(const float4*)&lds_buf[P][4*(p)]; \
        Q##A0 = v.x; Q##A1 = v.y; Q##A2 = v.z; Q##A3 = v.w; }
#define LOADQ(P) \
        LQ(P, 0, 0,1,2,3)     LQ(P, 1, 4,5,6,7)     LQ(P, 2, 8,9,10,11) \
        LQ(P, 3, 12,13,14,15) LQ(P, 4, 16,17,18,19) LQ(P, 5, 20,21,22,23) \
        LQ(P, 6, 24,25,26,27) LQ(P, 7, 28,29,30,31) LQ(P, 8, 32,33,34,35) \
        LQ(P, 9, 36,37,38,39) LQ(P,10, 40,41,42,43) LQ(P,11, 44,45,46,47)

// One recursion step at time TT consuming raw feat value FVAL.
// Invariant alpha_j = C + log(q_j), updated only when TT < len (wave-uniform).
#define STEP(TT, FVAL) do { \
        const float q0v  = Q0; \
        const bool  live = (q0v > 0.0f);                 /* false only at t==0 */ \
        const float inv  = live ? __builtin_amdgcn_rcpf(q0v) : 1.0f; \
        const float dC   = live ? __logf(q0v) : 0.0f; \
        const bool  on   = ((TT) < len); \
        C += on ? dC : 0.0f; \
        const float scale = __expf(FVAL) * inv; \
        float a0 = 0.f, a1 = 0.f, a2 = 0.f, a3 = 0.f; \
        FMA4(0,1,2,3)     FMA4(4,5,6,7)     FMA4(8,9,10,11)   FMA4(12,13,14,15) \
        FMA4(16,17,18,19) FMA4(20,21,22,23) FMA4(24,25,26,27) FMA4(28,29,30,31) \
        FMA4(32,33,34,35) FMA4(36,37,38,39) FMA4(40,41,42,43) \
        a0 = fmaf(E44, Q44, a0); a1 = fmaf(E45, Q45, a1); a2 = fmaf(E46, Q46, a2); \
        const float w  = (a0 + a1) + (a2 + a3); \
        const float qn = on ? w * scale : qown; \
        qown = qn; \
        lds_buf[(TT) & 1][lane] = qn; \
        asm volatile("s_waitcnt lgkmcnt(0)" ::: "memory"); \
        LOADQ((TT) & 1) \
    } while (0)

__global__ __launch_bounds__(64)
__attribute__((amdgpu_waves_per_eu(1, 1)))
void crf_fused_kernel(
    const float* __restrict__ feats,    // (T, B, K)
    const float* __restrict__ trans,    // (K, K)
    const int*   __restrict__ tags,     // (B, T)
    const int*   __restrict__ lengths,  // (B,)
    float* __restrict__ out)
{
    const int b      = blockIdx.x;
    const int lane   = threadIdx.x;
    const int len    = lengths[b];
    const int lm1    = len - 1;
    const int lane_c = (lane < K_N) ? lane : (K_N - 1);   // clamp: all addrs valid

    __shared__ __attribute__((aligned(16))) float lds_buf[2][64];  // 512 B

    // E row in named scalars (VGPR-resident). Col 47 (STOP) excluded: exp(-1e4)=0.
    const float* tr = trans + lane_c * K_N;
#define DECL_E(k) const float E##k = __expf(tr[k]);
    REP47(DECL_E)
#undef DECL_E

    // Replicated q vector: identical in every lane. Init: q_START = 1, rest 0.
#define DECL_Q(k) float Q##k = ((k) == START_TAG) ? 1.0f : 0.0f;
    REP47(DECL_Q)
#undef DECL_Q
    float Q47 = 0.0f;   // STOP state; loaded by LOADQ, never used in FMAs.

    const float*  fb = feats + (size_t)b * K_N;
    const size_t  sT = (size_t)B_N * K_N;

    float qown = (lane == START_TAG) ? 1.0f : 0.0f;   // this lane's own q_j
    float C = 0.0f;

    // Ping-pong prefetch buffers, all statically indexed (registers).
    float f0[8], f1[8];
    #pragma unroll
    for (int i = 0; i < 8; ++i) {
        int r = (i < lm1) ? i : lm1;
        f0[i] = fb[(size_t)r * sT + lane_c];
    }

    #pragma unroll 1
    for (int blk = 0; blk < T_LEN / 16; ++blk) {
        const int t0 = blk * 16;
        // Phase A: prefetch rows t0+8..t0+15 into f1; run steps t0..t0+7 on f0.
        #pragma unroll
        for (int i = 0; i < 8; ++i) {
            int r = t0 + 8 + i; r = (r < lm1) ? r : lm1;
            f1[i] = fb[(size_t)r * sT + lane_c];
        }
        #pragma unroll
        for (int i = 0; i < 8; ++i) STEP(t0 + i, f0[i]);
        // Phase B: prefetch rows t0+16..t0+23 into f0; run steps t0+8..t0+15 on f1.
        #pragma unroll
        for (int i = 0; i < 8; ++i) {
            int r = t0 + 16 + i; r = (r < lm1) ? r : lm1;
            f0[i] = fb[(size_t)r * sT + lane_c];
        }
        #pragma unroll
        for (int i = 0; i < 8; ++i) STEP(t0 + 8 + i, f1[i]);
    }

    // log_z = C + log(q_j) + trans[STOP, j], logsumexp over lanes.
    float v = (lane < K_N && qown > 0.0f)
            ? C + __logf(qown) + trans[STOP_TAG * K_N + lane] : -INFINITY;
    float mz = v;
    #pragma unroll
    for (int off = 32; off >= 1; off >>= 1)
        mz = fmaxf(mz, __shfl_xor(mz, off));
    float e = __expf(v - mz);
    float se = e;
    #pragma unroll
    for (int off = 32; off >= 1; off >>= 1)
        se += __shfl_xor(se, off);
    float log_z = mz + __logf(se);

    // Gold path score: lanes stripe over t.
    float gsum = 0.0f;
    for (int t = lane; t < len; t += 64) {
        int next = tags[(size_t)b * T_LEN + t];
        int prev = (t == 0) ? START_TAG : tags[(size_t)b * T_LEN + t - 1];
        gsum += trans[next * K_N + prev]
              + fb[(size_t)t * sT + next];
    }
    #pragma unroll
    for (int off = 32; off >= 1; off >>= 1)
        gsum += __shfl_xor(gsum, off);

    if (lane == 0) {
        int last = tags[(size_t)b * T_LEN + len - 1];
        float gold = gsum + trans[STOP_TAG * K_N + last];
        atomicAdd(out, log_z - gold);
    }
}

extern "C" void kernel_launch(void* const* d_in, const int* in_sizes, int n_in,
                              void* d_out, int out_size, void* d_ws, size_t ws_size,
                              hipStream_t stream) {
    const float* feats   = (const float*)d_in[0];
    const float* trans   = (const float*)d_in[1];
    const int*   tags    = (const int*)d_in[2];
    const int*   lengths = (const int*)d_in[3];
    float* out = (float*)d_out;

    hipMemsetAsync(out, 0, sizeof(float) * out_size, stream);
    crf_fused_kernel<<<B_N, 64, 0, stream>>>(feats, trans, tags, lengths, out);
}

// Round 3
// 259.749 us; speedup vs baseline: 1.3317x; 1.1006x over previous
//
#include <hip/hip_runtime.h>
#include <math.h>

#define T_LEN 512
#define B_N   1024
#define K_N   48
#define START_TAG (K_N - 2)
#define STOP_TAG  (K_N - 1)
#define NEG   -10000.0f

// Single-wave CRF forward, systolic-rotation variant (no readlane, no LDS on
// the recursion chain — R1/R2 proved any barrier/LDS round-trip on the
// 512-deep serial chain costs 200-500 cy/step).
//
// State: lane j holds q_j = exp(alpha_j - C), padded to a 64-ring
// (lanes 48..63 hold q=0 with all-zero coefficients — never contribute).
// Per step the wave rotates q through all 64 offsets with v_mov_b32_dpp
// wave_ror:1 / wave_rol:1 — TWO independent 32-deep chains (ror: offsets
// +0..+31, rol: the rest), interleaved so each chain's ~4cy dep latency
// hides under the other's issue. 64 dpp movs + 64 VGPR fmas ~ 256 issue cy,
// zero memory ops on the chain (R0's 47 readlanes cost ~5.5cy each = ~260cy
// alone, plus stall -> 640 cy/step).
//
// Direction-proof E tables: ror/rol direction semantics are NOT assumed.
// Setup runs the SAME dpp ops on the lane-id vector to discover, per
// rotation count r, which source lane's q arrives — then loads
// EA[r] = exp(trans[lane][src]) (0 if src/lane out of range). Whichever way
// the HW rotates, coefficients match data by construction, and ror+rol
// jointly cover all 64 offsets exactly once.
//
// Deferred normalization: rcp/log/readlane only every 4 steps (q_0 > 0 after
// step 0 since E[0,START]>0; worst-case 4-step growth ~e^35 * spread e^10
// << fp32 max; frozen batches renorm to q_0=1 and stay exact).
//
// Carried-over load-bearing details:
//  * waves_per_eu(1,1): default VGPR budget would spill the 64 E regs.
//  * feat loads UNCONDITIONAL (clamped indices), 8 steps ahead, statically
//    indexed ping-pong arrays (no register rotation, R6).
//  * per-step `t < len` cndmask freeze == reference mask semantics.
//  * __expf(feat) depends only on the prefetch, so it schedules off-chain.

__device__ __forceinline__ int ror1_i(int x) {
    return __builtin_amdgcn_mov_dpp(x, 0x13C, 0xF, 0xF, true);  // wave_ror:1
}
__device__ __forceinline__ int rol1_i(int x) {
    return __builtin_amdgcn_mov_dpp(x, 0x134, 0xF, 0xF, true);  // wave_rol:1
}
__device__ __forceinline__ float ror1_f(float x) {
    return __int_as_float(ror1_i(__float_as_int(x)));
}
__device__ __forceinline__ float rol1_f(float x) {
    return __int_as_float(rol1_i(__float_as_int(x)));
}

// One recursion step: q_j <- on ? scale_j * sum_k E[j,k] q_k : q_j
__device__ __forceinline__ void crf_step(float& q,
                                         const float (&EA)[32],
                                         const float (&EB)[32],
                                         float scale, bool on)
{
    float hA = q;             // chain A starts at offset 0
    float hB = rol1_f(q);     // chain B starts one rol ahead
    float a0 = 0.f, a1 = 0.f, a2 = 0.f, a3 = 0.f;
    #pragma unroll
    for (int r = 0; r < 32; r += 2) {
        a0 = fmaf(EA[r],     hA, a0);
        a2 = fmaf(EB[r],     hB, a2);
        hA = ror1_f(hA);
        hB = rol1_f(hB);
        a1 = fmaf(EA[r + 1], hA, a1);
        a3 = fmaf(EB[r + 1], hB, a3);
        hA = ror1_f(hA);      // dead on last iter -> DCE
        hB = rol1_f(hB);
    }
    const float w  = (a0 + a1) + (a2 + a3);
    const float qn = w * scale;
    q = on ? qn : q;
}

// Representation change only: q /= q_0, C += log(q_0). alpha = C + log(q)
// invariant preserved, so it is safe (and required) even for frozen batches.
__device__ __forceinline__ void renorm(float& q, float& C)
{
    const float g = __uint_as_float(__builtin_amdgcn_readlane(__float_as_uint(q), 0));
    C += __logf(g);
    q *= __builtin_amdgcn_rcpf(g);
}

__global__ __launch_bounds__(64)
__attribute__((amdgpu_waves_per_eu(1, 1)))
void crf_fused_kernel(
    const float* __restrict__ feats,    // (T, B, K)
    const float* __restrict__ trans,    // (K, K)
    const int*   __restrict__ tags,     // (B, T)
    const int*   __restrict__ lengths,  // (B,)
    float* __restrict__ out)
{
    const int b      = blockIdx.x;
    const int lane   = threadIdx.x;
    const int len    = lengths[b];
    const int lm1    = len - 1;
    const int lane_c = (lane < K_N) ? lane : (K_N - 1);   // clamp: addrs valid

    // ---- Direction-proof E tables (64 VGPRs), built with the real dpp ops.
    float EA[32], EB[32];
    {
        int srcA = lane;           // source lane feeding chain A's FMA r
        int srcB = rol1_i(lane);   // chain B is one rol ahead
        #pragma unroll
        for (int r = 0; r < 32; ++r) {
            const int sa = (srcA < K_N) ? srcA : 0;
            const int sb = (srcB < K_N) ? srcB : 0;
            const float va = trans[lane_c * K_N + sa];
            const float vb = trans[lane_c * K_N + sb];
            EA[r] = (lane < K_N && srcA < K_N) ? __expf(va) : 0.0f;
            EB[r] = (lane < K_N && srcB < K_N) ? __expf(vb) : 0.0f;
            srcA = ror1_i(srcA);
            srcB = rol1_i(srcB);
        }
    }

    const float*  fb = feats + (size_t)b * K_N;
    const size_t  sT = (size_t)B_N * K_N;

    // Lane j's own q_j. Pads (>=48) start 0 and stay 0 (zero coefficients).
    float q = (lane == START_TAG) ? 1.0f : 0.0f;
    float C = 0.0f;

    // Ping-pong raw-feat prefetch buffers, statically indexed.
    float f0[8], f1[8];
    #pragma unroll
    for (int i = 0; i < 8; ++i) {
        int r = (i < lm1) ? i : lm1;
        f0[i] = fb[(size_t)r * sT + lane_c];
    }

    #pragma unroll 1
    for (int blk = 0; blk < T_LEN / 16; ++blk) {
        const int t0 = blk * 16;
        // Phase A: prefetch rows t0+8..t0+15 into f1; steps t0..t0+7 on f0.
        #pragma unroll
        for (int i = 0; i < 8; ++i) {
            int r = t0 + 8 + i; r = (r < lm1) ? r : lm1;
            f1[i] = fb[(size_t)r * sT + lane_c];
        }
        #pragma unroll
        for (int i = 0; i < 8; ++i) {
            crf_step(q, EA, EB, __expf(f0[i]), (t0 + i) < len);
            if (i == 3 || i == 7) renorm(q, C);
        }
        // Phase B: prefetch rows t0+16..t0+23 into f0; steps t0+8..t0+15 on f1.
        #pragma unroll
        for (int i = 0; i < 8; ++i) {
            int r = t0 + 16 + i; r = (r < lm1) ? r : lm1;
            f0[i] = fb[(size_t)r * sT + lane_c];
        }
        #pragma unroll
        for (int i = 0; i < 8; ++i) {
            crf_step(q, EA, EB, __expf(f1[i]), (t0 + 8 + i) < len);
            if (i == 3 || i == 7) renorm(q, C);
        }
    }

    // log_z = C + log(q_j) + trans[STOP, j], logsumexp over lanes.
    // q_46 == 0 (START row is all -1e4) and pads are excluded by lane < K_N.
    float v = (lane < K_N && q > 0.0f)
            ? C + __logf(q) + trans[STOP_TAG * K_N + lane] : -INFINITY;
    float mz = v;
    #pragma unroll
    for (int off = 32; off >= 1; off >>= 1)
        mz = fmaxf(mz, __shfl_xor(mz, off));
    float e = __expf(v - mz);
    float se = e;
    #pragma unroll
    for (int off = 32; off >= 1; off >>= 1)
        se += __shfl_xor(se, off);
    float log_z = mz + __logf(se);

    // Gold path score: lanes stripe over t.
    float gsum = 0.0f;
    for (int t = lane; t < len; t += 64) {
        int next = tags[(size_t)b * T_LEN + t];
        int prev = (t == 0) ? START_TAG : tags[(size_t)b * T_LEN + t - 1];
        gsum += trans[next * K_N + prev]
              + fb[(size_t)t * sT + next];
    }
    #pragma unroll
    for (int off = 32; off >= 1; off >>= 1)
        gsum += __shfl_xor(gsum, off);

    if (lane == 0) {
        int last = tags[(size_t)b * T_LEN + len - 1];
        float gold = gsum + trans[STOP_TAG * K_N + last];
        atomicAdd(out, log_z - gold);
    }
}

extern "C" void kernel_launch(void* const* d_in, const int* in_sizes, int n_in,
                              void* d_out, int out_size, void* d_ws, size_t ws_size,
                              hipStream_t stream) {
    const float* feats   = (const float*)d_in[0];
    const float* trans   = (const float*)d_in[1];
    const int*   tags    = (const int*)d_in[2];
    const int*   lengths = (const int*)d_in[3];
    float* out = (float*)d_out;

    hipMemsetAsync(out, 0, sizeof(float) * out_size, stream);
    crf_fused_kernel<<<B_N, 64, 0, stream>>>(feats, trans, tags, lengths, out);
}

// Round 4
// 212.233 us; speedup vs baseline: 1.6298x; 1.2239x over previous
//
#include <hip/hip_runtime.h>
#include <math.h>

#define T_LEN 512
#define B_N   1024
#define K_N   48
#define START_TAG (K_N - 2)
#define STOP_TAG  (K_N - 1)
#define NEG   -10000.0f

// Forward/backward split CRF. One workgroup (2 waves) per batch:
//   wave 0: forward  alpha over t = 0 .. m-1          (m = ceil(len/2) steps)
//   wave 1: backward beta  over t = len-1 .. m        (len-m steps)
//   log_z = C_f + C_b + log( sum_j q_j * p_j )        (ONE barrier, at the end)
// Identity: log_z = LSE_j( alpha_{m-1}(j) + beta_m(j) ),
//   beta_t(j) = LSE_i( trans[i,j] + feat[t,i] + beta_{t+1}(i) ),
//   beta_len(j) = trans[STOP,j].
// Backward in exp-domain has the same shape as forward with E^T and the
// exp(feat) multiply applied BEFORE the matvec. Zero coefficients (row START,
// col STOP of trans = -1e4) arise naturally from expf().
//
// Why this decomposition (R0-R3 evidence):
//  * R0 (readlane broadcast, 1 wave/batch): 640 cy/step, ~250 cy of it
//    unfillable stall at 1 wave/SIMD, wall pinned to max len = 512 steps.
//  * R1/R2/R3 proved: barrier, LDS round-trip, or deep dpp chains on the
//    512-deep serial recursion all LOSE to the readlane engine. Keep it.
//  * Here: serial depth halves (<=256, mean 128), loop trips scale with len
//    (not fixed 512), and 2048 waves = 2/SIMD so two independent chains
//    interleave and fill each other's stalls. One end-of-kernel barrier only.
//  * R3-proven renorm deferral (every 4 steps): worst-case 4-step growth
//    ~e^36 << fp32 max; renorm is representation-only so it is safe while
//    frozen. Final renorm bounds the combine dot (< e^24).
//
// Carried-over load-bearing details:
//  * feat loads UNCONDITIONAL (clamped row indices), 8 steps ahead,
//    statically-indexed f0/f1 ping-pong (no register rotation — R6).
//  * per-step `t < steps` cndmask freeze == reference mask semantics.
//  * waves_per_eu(2,2): VGPR cap 256 (we need ~130), guarantees 2 waves/EU.

__device__ __forceinline__ float bcast(float v, int k) {
    return __uint_as_float(__builtin_amdgcn_readlane(__float_as_uint(v), k));
}

// w_lane = sum_{k<48} E[k] * (lane k of src); 48 readlanes + 48 fma, 4 chains.
__device__ __forceinline__ float matvec48(const float (&E)[48], float src) {
    float a0 = 0.f, a1 = 0.f, a2 = 0.f, a3 = 0.f;
    #pragma unroll
    for (int k = 0; k < 48; k += 4) {
        a0 = fmaf(E[k + 0], bcast(src, k + 0), a0);
        a1 = fmaf(E[k + 1], bcast(src, k + 1), a1);
        a2 = fmaf(E[k + 2], bcast(src, k + 2), a2);
        a3 = fmaf(E[k + 3], bcast(src, k + 3), a3);
    }
    return (a0 + a1) + (a2 + a3);
}

// Representation change only: q /= q_0, C += log(q_0). Safe while frozen.
__device__ __forceinline__ void renorm(float& q, float& C) {
    const float g = bcast(q, 0);
    C += __logf(g);
    q *= __builtin_amdgcn_rcpf(g);
}

// Run `steps` recursion steps (<= 256). BWD=0: q' = exp(f)*(E q).
// BWD=1: q' = E^T (exp(f) .* q), rows consumed len-1 downward.
template <int BWD>
__device__ __forceinline__ void run_chain(const float* __restrict__ fb,
                                          const float (&E)[48],
                                          int steps, int lm1, int lane_c,
                                          float& q, float& C)
{
    const size_t sT = (size_t)B_N * K_N;
    auto row_of = [&](int i) -> int {
        int r = BWD ? (lm1 - i) : i;
        r = (r < 0) ? 0 : r;
        r = (r > lm1) ? lm1 : r;
        return r;
    };
    auto step = [&](int t, float fv) {
        const bool on = t < steps;                 // wave-uniform freeze
        if (BWD) {
            const float u = q * __expf(fv);        // feat BEFORE matvec
            const float w = matvec48(E, u);
            q = on ? w : q;
        } else {
            const float w = matvec48(E, q);
            q = on ? w * __expf(fv) : q;           // feat AFTER matvec
        }
    };

    float f0[8], f1[8];
    #pragma unroll
    for (int i = 0; i < 8; ++i)
        f0[i] = fb[(size_t)row_of(i) * sT + lane_c];

    const int nblk = (steps + 15) >> 4;
    #pragma unroll 1
    for (int blk = 0; blk < nblk; ++blk) {
        const int t0 = blk * 16;
        #pragma unroll
        for (int i = 0; i < 8; ++i)
            f1[i] = fb[(size_t)row_of(t0 + 8 + i) * sT + lane_c];
        #pragma unroll
        for (int i = 0; i < 8; ++i) {
            step(t0 + i, f0[i]);
            if (i == 3 || i == 7) renorm(q, C);
        }
        #pragma unroll
        for (int i = 0; i < 8; ++i)
            f0[i] = fb[(size_t)row_of(t0 + 16 + i) * sT + lane_c];
        #pragma unroll
        for (int i = 0; i < 8; ++i) {
            step(t0 + 8 + i, f1[i]);
            if (i == 3 || i == 7) renorm(q, C);
        }
    }
}

__global__ __launch_bounds__(128)
__attribute__((amdgpu_waves_per_eu(2, 2)))
void crf_fused_kernel(
    const float* __restrict__ feats,    // (T, B, K)
    const float* __restrict__ trans,    // (K, K)
    const int*   __restrict__ tags,     // (B, T)
    const int*   __restrict__ lengths,  // (B,)
    float* __restrict__ out)
{
    const int b      = blockIdx.x;
    const int tid    = threadIdx.x;
    const int lane   = tid & 63;
    const int wid    = tid >> 6;                  // 0 = forward, 1 = backward
    const int len    = lengths[b];
    const int lm1    = len - 1;
    const int m      = (len + 1) >> 1;            // split point
    const int steps  = wid ? (len - m) : m;       // fwd >= 1; bwd >= 0
    const int lane_c = (lane < K_N) ? lane : (K_N - 1);

    __shared__ __attribute__((aligned(16))) float sh_p[64];
    __shared__ float sh_cb;
    __shared__ float sh_gold;

    // Coefficients: fwd lane j holds row j of E = exp(trans);
    // bwd lane j holds row j of E^T, i.e. exp(trans[k][j]).
    // Zeros (col STOP fwd / row START bwd) come out of expf(-1e4) = 0.
    float E[48];
    if (wid == 0) {
        const float* tr = trans + lane_c * K_N;
        #pragma unroll
        for (int k = 0; k < 48; ++k) E[k] = __expf(tr[k]);
    } else {
        #pragma unroll
        for (int k = 0; k < 48; ++k) E[k] = __expf(trans[k * K_N + lane_c]);
    }

    const float* fb = feats + (size_t)b * K_N;
    const size_t sT = (size_t)B_N * K_N;

    // State init. Pads (lanes >= 48) mirror lane 47: junk but finite, masked
    // out of every readlane (k < 48) and of the final dot.
    float q, C = 0.0f;
    if (wid == 0) q = (lane == START_TAG) ? 1.0f : 0.0f;     // alpha init
    else          q = __expf(trans[STOP_TAG * K_N + lane_c]); // beta_len

    if (wid == 0) run_chain<0>(fb, E, steps, lm1, lane_c, q, C);
    else          run_chain<1>(fb, E, steps, lm1, lane_c, q, C);
    renorm(q, C);   // bound q for the combine dot (q_0 == 1 after this)

    if (wid == 1) {
        // Gold path score (proven code from R0), striped over t.
        float gsum = 0.0f;
        for (int t = lane; t < len; t += 64) {
            int next = tags[(size_t)b * T_LEN + t];
            int prev = (t == 0) ? START_TAG : tags[(size_t)b * T_LEN + t - 1];
            gsum += trans[next * K_N + prev] + fb[(size_t)t * sT + next];
        }
        #pragma unroll
        for (int off = 32; off >= 1; off >>= 1)
            gsum += __shfl_xor(gsum, off);

        sh_p[lane] = q;
        if (lane == 0) {
            sh_cb = C;
            int last = tags[(size_t)b * T_LEN + len - 1];
            sh_gold = gsum + trans[STOP_TAG * K_N + last];
        }
    }
    __syncthreads();

    if (wid == 0) {
        // log_z = C_f + C_b + log( sum_j q_j p_j ), sum > 0 (q_0 p_0 > 0).
        float term = (lane < K_N) ? q * sh_p[lane] : 0.0f;
        #pragma unroll
        for (int off = 32; off >= 1; off >>= 1)
            term += __shfl_xor(term, off);
        if (lane == 0) {
            float log_z = C + sh_cb + __logf(term);
            atomicAdd(out, log_z - sh_gold);
        }
    }
}

extern "C" void kernel_launch(void* const* d_in, const int* in_sizes, int n_in,
                              void* d_out, int out_size, void* d_ws, size_t ws_size,
                              hipStream_t stream) {
    const float* feats   = (const float*)d_in[0];
    const float* trans   = (const float*)d_in[1];
    const int*   tags    = (const int*)d_in[2];
    const int*   lengths = (const int*)d_in[3];
    float* out = (float*)d_out;

    hipMemsetAsync(out, 0, sizeof(float) * out_size, stream);
    crf_fused_kernel<<<B_N, 128, 0, stream>>>(feats, trans, tags, lengths, out);
}

// Round 5
// 195.440 us; speedup vs baseline: 1.7698x; 1.0859x over previous
//
#include <hip/hip_runtime.h>
#include <math.h>

#define T_LEN 512
#define B_N   1024
#define K_N   48
#define START_TAG (K_N - 2)
#define STOP_TAG  (K_N - 1)
#define NEG   -10000.0f

// Forward/backward split CRF + LPT scheduling at 1 wave/SIMD.
//
// R4 post-mortem: dur 116us == 256 steps x 1088 cy == the longest batch's
// half-chain at the W=2-per-SIMD pace. Co-residency raised per-wave step cost
// 640 -> 1088 cy (issue/readlane contention), so the kernel is CRITICAL-PATH
// bound, not bulk bound. At W=1 both bounds coincide at ~68us:
//   critical: 256 steps x 640cy = 164K cy;  bulk: 262K steps/1024 SIMDs x 640.
// So: (a) waves_per_eu(1,1) pins every resident chain at the dedicated-SIMD
// rate; (b) a ~5us device-side counting sort orders batches by descending
// length (perm in d_ws) so long chains dispatch first (LPT); short ones
// backfill retired slots. Pairing fwd/bwd in one WG is free: the two halves
// differ by <= 1 step.
//
// Engine (unchanged, best of R0-R3): readlane broadcast, 48 fma x 4 chains,
// renorm every 4 steps, 8-ahead statically-indexed prefetch, freeze-masking.
// R1/R2/R3 lessons: no barrier / LDS round-trip / dpp chain on the recursion.

__device__ __forceinline__ float bcast(float v, int k) {
    return __uint_as_float(__builtin_amdgcn_readlane(__float_as_uint(v), k));
}

__device__ __forceinline__ float matvec48(const float (&E)[48], float src) {
    float a0 = 0.f, a1 = 0.f, a2 = 0.f, a3 = 0.f;
    #pragma unroll
    for (int k = 0; k < 48; k += 4) {
        a0 = fmaf(E[k + 0], bcast(src, k + 0), a0);
        a1 = fmaf(E[k + 1], bcast(src, k + 1), a1);
        a2 = fmaf(E[k + 2], bcast(src, k + 2), a2);
        a3 = fmaf(E[k + 3], bcast(src, k + 3), a3);
    }
    return (a0 + a1) + (a2 + a3);
}

// Representation change only: q /= q_0, C += log(q_0). Safe while frozen.
__device__ __forceinline__ void renorm(float& q, float& C) {
    const float g = bcast(q, 0);
    C += __logf(g);
    q *= __builtin_amdgcn_rcpf(g);
}

// Run `steps` recursion steps (<= 256). BWD=0: q' = exp(f)*(E q).
// BWD=1: q' = E^T (exp(f) .* q), rows consumed len-1 downward.
template <int BWD>
__device__ __forceinline__ void run_chain(const float* __restrict__ fb,
                                          const float (&E)[48],
                                          int steps, int lm1, int lane_c,
                                          float& q, float& C)
{
    const size_t sT = (size_t)B_N * K_N;
    auto row_of = [&](int i) -> int {
        int r = BWD ? (lm1 - i) : i;
        r = (r < 0) ? 0 : r;
        r = (r > lm1) ? lm1 : r;
        return r;
    };
    auto step = [&](int t, float fv) {
        const bool on = t < steps;                 // wave-uniform freeze
        if (BWD) {
            const float u = q * __expf(fv);        // feat BEFORE matvec
            const float w = matvec48(E, u);
            q = on ? w : q;
        } else {
            const float w = matvec48(E, q);
            q = on ? w * __expf(fv) : q;           // feat AFTER matvec
        }
    };

    float f0[8], f1[8];
    #pragma unroll
    for (int i = 0; i < 8; ++i)
        f0[i] = fb[(size_t)row_of(i) * sT + lane_c];

    const int nblk = (steps + 15) >> 4;
    #pragma unroll 1
    for (int blk = 0; blk < nblk; ++blk) {
        const int t0 = blk * 16;
        #pragma unroll
        for (int i = 0; i < 8; ++i)
            f1[i] = fb[(size_t)row_of(t0 + 8 + i) * sT + lane_c];
        #pragma unroll
        for (int i = 0; i < 8; ++i) {
            step(t0 + i, f0[i]);
            if (i == 3 || i == 7) renorm(q, C);
        }
        #pragma unroll
        for (int i = 0; i < 8; ++i)
            f0[i] = fb[(size_t)row_of(t0 + 16 + i) * sT + lane_c];
        #pragma unroll
        for (int i = 0; i < 8; ++i) {
            step(t0 + 8 + i, f1[i]);
            if (i == 3 || i == 7) renorm(q, C);
        }
    }
}

// ---- LPT sort: perm = batch ids by DESCENDING length (counting sort). ----
__global__ __launch_bounds__(1024)
void lpt_sort_kernel(const int* __restrict__ lengths, int* __restrict__ perm)
{
    __shared__ int hist[512];
    __shared__ int offs[512];
    const int tid = threadIdx.x;
    if (tid < 512) hist[tid] = 0;
    __syncthreads();
    const int len = lengths[tid];          // len in [1, 512]
    const int key = 512 - len;             // [0, 511], 0 = longest
    atomicAdd(&hist[key], 1);
    __syncthreads();
    if (tid < 512) offs[tid] = hist[tid];
    __syncthreads();
    // inclusive Hillis-Steele scan of offs[0..511]
    for (int d = 1; d < 512; d <<= 1) {
        int v = 0;
        if (tid < 512 && tid >= d) v = offs[tid - d];
        __syncthreads();
        if (tid < 512) offs[tid] += v;
        __syncthreads();
    }
    // bucket [inclusive-hist, inclusive): fill top-down via atomicSub
    const int p = atomicSub(&offs[key], 1) - 1;
    perm[p] = tid;
}

__global__ __launch_bounds__(128)
__attribute__((amdgpu_waves_per_eu(1, 1)))
void crf_fused_kernel(
    const float* __restrict__ feats,    // (T, B, K)
    const float* __restrict__ trans,    // (K, K)
    const int*   __restrict__ tags,     // (B, T)
    const int*   __restrict__ lengths,  // (B,)
    const int*   __restrict__ perm,     // (B,) LPT order
    float* __restrict__ out)
{
    const int b      = perm[blockIdx.x];          // LPT: longest first
    const int tid    = threadIdx.x;
    const int lane   = tid & 63;
    const int wid    = tid >> 6;                  // 0 = forward, 1 = backward
    const int len    = lengths[b];
    const int lm1    = len - 1;
    const int m      = (len + 1) >> 1;            // split point
    const int steps  = wid ? (len - m) : m;       // fwd >= 1; bwd >= 0
    const int lane_c = (lane < K_N) ? lane : (K_N - 1);

    __shared__ __attribute__((aligned(16))) float sh_p[64];
    __shared__ float sh_cb;
    __shared__ float sh_gold;

    // Coefficients: fwd lane j holds row j of E = exp(trans);
    // bwd lane j holds row j of E^T. Zeros come out of expf(-1e4) = 0.
    float E[48];
    if (wid == 0) {
        const float* tr = trans + lane_c * K_N;
        #pragma unroll
        for (int k = 0; k < 48; ++k) E[k] = __expf(tr[k]);
    } else {
        #pragma unroll
        for (int k = 0; k < 48; ++k) E[k] = __expf(trans[k * K_N + lane_c]);
    }

    const float* fb = feats + (size_t)b * K_N;
    const size_t sT = (size_t)B_N * K_N;

    float q, C = 0.0f;
    if (wid == 0) q = (lane == START_TAG) ? 1.0f : 0.0f;      // alpha init
    else          q = __expf(trans[STOP_TAG * K_N + lane_c]); // beta_len

    if (wid == 0) run_chain<0>(fb, E, steps, lm1, lane_c, q, C);
    else          run_chain<1>(fb, E, steps, lm1, lane_c, q, C);
    renorm(q, C);   // bound q for the combine dot (q_0 == 1 after this)

    if (wid == 1) {
        // Gold path score, striped over t.
        float gsum = 0.0f;
        for (int t = lane; t < len; t += 64) {
            int next = tags[(size_t)b * T_LEN + t];
            int prev = (t == 0) ? START_TAG : tags[(size_t)b * T_LEN + t - 1];
            gsum += trans[next * K_N + prev] + fb[(size_t)t * sT + next];
        }
        #pragma unroll
        for (int off = 32; off >= 1; off >>= 1)
            gsum += __shfl_xor(gsum, off);

        sh_p[lane] = q;
        if (lane == 0) {
            sh_cb = C;
            int last = tags[(size_t)b * T_LEN + len - 1];
            sh_gold = gsum + trans[STOP_TAG * K_N + last];
        }
    }
    __syncthreads();

    if (wid == 0) {
        // log_z = C_f + C_b + log( sum_j q_j p_j ), sum > 0 (q_0 p_0 > 0).
        float term = (lane < K_N) ? q * sh_p[lane] : 0.0f;
        #pragma unroll
        for (int off = 32; off >= 1; off >>= 1)
            term += __shfl_xor(term, off);
        if (lane == 0) {
            float log_z = C + sh_cb + __logf(term);
            atomicAdd(out, log_z - sh_gold);
        }
    }
}

extern "C" void kernel_launch(void* const* d_in, const int* in_sizes, int n_in,
                              void* d_out, int out_size, void* d_ws, size_t ws_size,
                              hipStream_t stream) {
    const float* feats   = (const float*)d_in[0];
    const float* trans   = (const float*)d_in[1];
    const int*   tags    = (const int*)d_in[2];
    const int*   lengths = (const int*)d_in[3];
    float* out = (float*)d_out;
    int*   perm = (int*)d_ws;                    // 4 KB of workspace

    hipMemsetAsync(out, 0, sizeof(float) * out_size, stream);
    lpt_sort_kernel<<<1, B_N, 0, stream>>>(lengths, perm);
    crf_fused_kernel<<<B_N, 128, 0, stream>>>(feats, trans, tags, lengths, perm, out);
}

// Round 6
// 192.202 us; speedup vs baseline: 1.7997x; 1.0168x over previous
//
#include <hip/hip_runtime.h>
#include <math.h>

#define T_LEN 512
#define B_N   1024
#define K_N   48
#define START_TAG (K_N - 2)
#define STOP_TAG  (K_N - 1)
#define NEG   -10000.0f

// Forward/backward split CRF + LPT at 1 wave/SIMD (R5, 77us kernel) with a
// leaner step engine:
//  * v_pk_fma_f32 (CDNA packed dual-fp32): 23 pk_fma replace 46 scalar fma.
//    Broadcast pair = two v_readlane packed into a uniform SGPR pair (SALU,
//    co-issues with VALU for free).
//  * 48 -> 46 k-terms: col STOP (k=47) is exp(-1e4)=0 always; k=46 (START)
//    only matters at t=0, so step 0 is PEELED in closed form:
//    q_j = exp(trans[j,START] + feat0_j)  (row START of E is zero afterward).
//    Backward: E^T terms k=46 (row START -> 0) and k=47 (p_47 == 0) drop too.
//  * Mask-free bulk: floor(steps/16) unmasked blocks (cndmask folds away) +
//    one masked tail block. Freeze semantics preserved in the tail.
// R5 accounting: 77us ~ critical path 256 steps x 640cy; 640 = 394 issue
// (48 readlane ~4cy + 48 fma ~2cy + misc) + 246 stall. This round cuts issue
// to ~270cy/step -> predicted ~440cy/step wall, ~55us kernel.
//
// Carried, load-bearing (R0-R5):
//  * NO barrier / LDS round-trip / dpp chain on the serial recursion (R1-R3).
//  * LPT: device counting sort, longest batches dispatch first; fwd/bwd pair
//    in one WG is balanced to +-1 step (R5: -39us).
//  * waves_per_eu(1,1): solo wave per SIMD = dedicated-rate critical chains.
//  * feat loads UNCONDITIONAL (row clamp to [0,T_LEN-1]), 8 ahead, statically
//    indexed f0/f1 ping-pong (R6 of prior session: no register rotation).
//  * renorm every 4 steps is representation-only (q /= q_0, C += log q_0):
//    safe even while frozen; q_0 > 0 invariant holds in both directions.

using f32x2 = __attribute__((ext_vector_type(2))) float;

__device__ __forceinline__ float bcast(float v, int k) {
    return __uint_as_float(__builtin_amdgcn_readlane(__float_as_uint(v), k));
}

// w_lane = sum_{k<46} E[lane,k] * (lane k of src).
// 46 readlane + 23 v_pk_fma_f32 over 4 accumulator chains.
__device__ __forceinline__ float matvec46(const f32x2 (&E2)[23], float src) {
    const int qb = __float_as_int(src);
    f32x2 a0 = {0.f, 0.f}, a1 = {0.f, 0.f}, a2 = {0.f, 0.f}, a3 = {0.f, 0.f};
#define PKFMA(P, ACC) { \
        const unsigned int lo = (unsigned int)__builtin_amdgcn_readlane(qb, 2*(P)); \
        const unsigned int hi = (unsigned int)__builtin_amdgcn_readlane(qb, 2*(P)+1); \
        const unsigned long long sp = ((unsigned long long)hi << 32) | lo; \
        asm("v_pk_fma_f32 %0, %1, %2, %0" : "+v"(ACC) : "v"(E2[P]), "s"(sp)); }
    PKFMA(0,a0)  PKFMA(1,a1)  PKFMA(2,a2)  PKFMA(3,a3)
    PKFMA(4,a0)  PKFMA(5,a1)  PKFMA(6,a2)  PKFMA(7,a3)
    PKFMA(8,a0)  PKFMA(9,a1)  PKFMA(10,a2) PKFMA(11,a3)
    PKFMA(12,a0) PKFMA(13,a1) PKFMA(14,a2) PKFMA(15,a3)
    PKFMA(16,a0) PKFMA(17,a1) PKFMA(18,a2) PKFMA(19,a3)
    PKFMA(20,a0) PKFMA(21,a1) PKFMA(22,a2)
#undef PKFMA
    const f32x2 s = (a0 + a1) + (a2 + a3);
    return s.x + s.y;
}

// Representation change only: q /= q_0, C += log(q_0). Safe while frozen.
__device__ __forceinline__ void renorm(float& q, float& C) {
    const float g = bcast(q, 0);
    C += __logf(g);
    q *= __builtin_amdgcn_rcpf(g);
}

// Run `steps` recursion steps. BWD=0: q' = exp(f) * (E q), rows rbase,+1,...
// BWD=1: q' = E^T (exp(f) .* q), rows rbase,-1,...
template <int BWD>
__device__ __forceinline__ void run_chain(const float* __restrict__ fb,
                                          int rbase,
                                          const f32x2 (&E2)[23],
                                          int steps, int lane_c,
                                          float& q, float& C)
{
    const size_t sT = (size_t)B_N * K_N;
    auto row_of = [&](int i) -> int {
        int r = BWD ? (rbase - i) : (rbase + i);
        r = (r < 0) ? 0 : r;
        r = (r > T_LEN - 1) ? (T_LEN - 1) : r;   // physically valid; junk rows
        return r;                                 // only feed frozen steps
    };
    auto step = [&](bool on, float fv) {
        if (BWD) {
            const float u = q * __expf(fv);       // feat BEFORE matvec
            const float w = matvec46(E2, u);
            q = on ? w : q;
        } else {
            const float w = matvec46(E2, q);
            q = on ? w * __expf(fv) : q;          // feat AFTER matvec
        }
    };

    float f0[8], f1[8];
    #pragma unroll
    for (int i = 0; i < 8; ++i)
        f0[i] = fb[(size_t)row_of(i) * sT + lane_c];

    const int nfull = steps >> 4;                 // unmasked 16-step blocks
    #pragma unroll 1
    for (int blk = 0; blk < nfull; ++blk) {
        const int t0 = blk * 16;
        #pragma unroll
        for (int i = 0; i < 8; ++i)
            f1[i] = fb[(size_t)row_of(t0 + 8 + i) * sT + lane_c];
        #pragma unroll
        for (int i = 0; i < 8; ++i) {
            step(true, f0[i]);                    // cndmask folds away
            if (i == 3 || i == 7) renorm(q, C);
        }
        #pragma unroll
        for (int i = 0; i < 8; ++i)
            f0[i] = fb[(size_t)row_of(t0 + 16 + i) * sT + lane_c];
        #pragma unroll
        for (int i = 0; i < 8; ++i) {
            step(true, f1[i]);
            if (i == 3 || i == 7) renorm(q, C);
        }
    }
    const int rem = steps & 15;                   // one masked tail block
    if (rem) {
        const int t0 = nfull * 16;
        #pragma unroll
        for (int i = 0; i < 8; ++i)
            f1[i] = fb[(size_t)row_of(t0 + 8 + i) * sT + lane_c];
        #pragma unroll
        for (int i = 0; i < 8; ++i) {
            step(i < rem, f0[i]);
            if (i == 3 || i == 7) renorm(q, C);
        }
        #pragma unroll
        for (int i = 0; i < 8; ++i) {
            step(8 + i < rem, f1[i]);
            if (i == 3 || i == 7) renorm(q, C);
        }
    }
}

// ---- LPT sort: perm = batch ids by DESCENDING length (counting sort). ----
__global__ __launch_bounds__(1024)
void lpt_sort_kernel(const int* __restrict__ lengths, int* __restrict__ perm)
{
    __shared__ int hist[512];
    __shared__ int offs[512];
    const int tid = threadIdx.x;
    if (tid < 512) hist[tid] = 0;
    __syncthreads();
    const int len = lengths[tid];          // len in [1, 512]
    const int key = 512 - len;             // [0, 511], 0 = longest
    atomicAdd(&hist[key], 1);
    __syncthreads();
    if (tid < 512) offs[tid] = hist[tid];
    __syncthreads();
    for (int d = 1; d < 512; d <<= 1) {    // inclusive Hillis-Steele scan
        int v = 0;
        if (tid < 512 && tid >= d) v = offs[tid - d];
        __syncthreads();
        if (tid < 512) offs[tid] += v;
        __syncthreads();
    }
    const int p = atomicSub(&offs[key], 1) - 1;
    perm[p] = tid;
}

__global__ __launch_bounds__(128)
__attribute__((amdgpu_waves_per_eu(1, 1)))
void crf_fused_kernel(
    const float* __restrict__ feats,    // (T, B, K)
    const float* __restrict__ trans,    // (K, K)
    const int*   __restrict__ tags,     // (B, T)
    const int*   __restrict__ lengths,  // (B,)
    const int*   __restrict__ perm,     // (B,) LPT order
    float* __restrict__ out)
{
    const int b      = perm[blockIdx.x];          // LPT: longest first
    const int tid    = threadIdx.x;
    const int lane   = tid & 63;
    const int wid    = tid >> 6;                  // 0 = forward, 1 = backward
    const int len    = lengths[b];
    const int lm1    = len - 1;
    const int m      = (len + 1) >> 1;            // split point
    const int lane_c = (lane < K_N) ? lane : (K_N - 1);

    __shared__ __attribute__((aligned(16))) float sh_p[64];
    __shared__ float sh_cb;
    __shared__ float sh_gold;

    const float* fb = feats + (size_t)b * K_N;
    const size_t sT = (size_t)B_N * K_N;

    // Coefficient pairs for k = 0..45 (46,47 provably contribute 0 after the
    // peeled step — see header). fwd: row lane of E; bwd: row lane of E^T.
    f32x2 E2[23];
    if (wid == 0) {
        const float* tr = trans + lane_c * K_N;
        #pragma unroll
        for (int p = 0; p < 23; ++p) {
            E2[p].x = __expf(tr[2 * p]);
            E2[p].y = __expf(tr[2 * p + 1]);
        }
    } else {
        #pragma unroll
        for (int p = 0; p < 23; ++p) {
            E2[p].x = __expf(trans[(2 * p) * K_N + lane_c]);
            E2[p].y = __expf(trans[(2 * p + 1) * K_N + lane_c]);
        }
    }

    float q, C = 0.0f;
    int   steps;
    if (wid == 0) {
        // Peeled step 0: q_j = exp(trans[j,START] + feat0_j). Lane 46 -> 0.
        q = __expf(trans[lane_c * K_N + START_TAG] + fb[lane_c]);
        steps = m - 1;                            // rows 1 .. m-1 remain
        run_chain<0>(fb, 1, E2, steps, lane_c, q, C);
    } else {
        q = __expf(trans[STOP_TAG * K_N + lane_c]);   // beta_len
        steps = len - m;                          // rows len-1 .. m
        run_chain<1>(fb, lm1, E2, steps, lane_c, q, C);
    }
    renorm(q, C);   // bound q for the combine dot (q_0 == 1 after this)

    if (wid == 1) {
        // Gold path score, striped over t.
        float gsum = 0.0f;
        for (int t = lane; t < len; t += 64) {
            int next = tags[(size_t)b * T_LEN + t];
            int prev = (t == 0) ? START_TAG : tags[(size_t)b * T_LEN + t - 1];
            gsum += trans[next * K_N + prev] + fb[(size_t)t * sT + next];
        }
        #pragma unroll
        for (int off = 32; off >= 1; off >>= 1)
            gsum += __shfl_xor(gsum, off);

        sh_p[lane] = q;
        if (lane == 0) {
            sh_cb = C;
            int last = tags[(size_t)b * T_LEN + len - 1];
            sh_gold = gsum + trans[STOP_TAG * K_N + last];
        }
    }
    __syncthreads();

    if (wid == 0) {
        // log_z = C_f + C_b + log( sum_j q_j p_j ); j=46,47 terms are 0 by
        // construction (q_46 = 0, p_47 = 0), pads excluded by lane < K_N.
        float term = (lane < K_N) ? q * sh_p[lane] : 0.0f;
        #pragma unroll
        for (int off = 32; off >= 1; off >>= 1)
            term += __shfl_xor(term, off);
        if (lane == 0) {
            float log_z = C + sh_cb + __logf(term);
            atomicAdd(out, log_z - sh_gold);
        }
    }
}

extern "C" void kernel_launch(void* const* d_in, const int* in_sizes, int n_in,
                              void* d_out, int out_size, void* d_ws, size_t ws_size,
                              hipStream_t stream) {
    const float* feats   = (const float*)d_in[0];
    const float* trans   = (const float*)d_in[1];
    const int*   tags    = (const int*)d_in[2];
    const int*   lengths = (const int*)d_in[3];
    float* out = (float*)d_out;
    int*   perm = (int*)d_ws;                    // 4 KB of workspace

    hipMemsetAsync(out, 0, sizeof(float) * out_size, stream);
    lpt_sort_kernel<<<1, B_N, 0, stream>>>(lengths, perm);
    crf_fused_kernel<<<B_N, 128, 0, stream>>>(feats, trans, tags, lengths, perm, out);
}